// Round 3
// baseline (1245.271 us; speedup 1.0000x reference)
//
#include <hip/hip_runtime.h>
#include <hip/hip_bf16.h>

// AttentionForQuantizer: q/k/v proj + RMSNorm + logits(32768x4096) + argmax + gather.
// R3: d_out is FP32 (reference outputs fp32/int32; harness rule "else float*").
// Evidence: R1/R2 identical output-0 absmax 4098.5 == packed bf16 idx pairs read as
// fp32 inside the fp32 logits chunk; R0 zeros gave exactly 4096.0 on output 1 (ref
// bf16-rounded idx). All outputs now written fp32. Logits via bf16 MFMA (direct
// global fragment loads, clamped fp32 store); refine re-dots candidates (within 0.5
// of fp32 row max) with the FROZEN canonical fp32 dot (dot256_f32 — summation order
// must never change across rounds); idx written as (float)bi; z_q = z_q_2 = v[idx].

#define NTOK 32768
#define NCODE 4096
#define DIM 256

typedef __bf16 bf16x8 __attribute__((ext_vector_type(8)));
typedef float f32x4 __attribute__((ext_vector_type(4)));

// ---------------- fp32 GEMM: Y[M][256] = X[M][256] @ W[256][256] + bias ----------------
// 128x128 tile per block, 256 threads, 8x8 per thread, BK=32.
__global__ __launch_bounds__(256, 2)
void gemm_xw256(const float* __restrict__ X, const float* __restrict__ W,
                const float* __restrict__ bias, float* __restrict__ Y)
{
    __shared__ __align__(16) float Xs[32][132];  // [kk][m], padded
    __shared__ __align__(16) float Ws[32][132];  // [kk][n], padded
    const int t  = threadIdx.x;
    const int tm = t >> 4;         // 0..15
    const int tn = t & 15;         // 0..15
    const int mb = blockIdx.x * 128;
    const int nb = blockIdx.y * 128;

    float acc[8][8];
    #pragma unroll
    for (int i = 0; i < 8; ++i)
        #pragma unroll
        for (int j = 0; j < 8; ++j) acc[i][j] = 0.f;

    const int sxm = t >> 1;          // X staging: row 0..127
    const int sxh = (t & 1) * 16;    // X staging: k-half base
    const int swk = t >> 3;          // W staging: kk 0..31
    const int swc = (t & 7) * 16;    // W staging: col base

    for (int kb = 0; kb < 256; kb += 32) {
        float4 xv[4], wv[4];
        #pragma unroll
        for (int i = 0; i < 4; ++i) {
            xv[i] = *(const float4*)&X[(size_t)(mb + sxm) * 256 + kb + sxh + 4 * i];
            wv[i] = *(const float4*)&W[(size_t)(kb + swk) * 256 + nb + swc + 4 * i];
        }
        __syncthreads();  // previous iteration's LDS reads done before overwrite
        #pragma unroll
        for (int i = 0; i < 4; ++i) {
            Xs[sxh + 4*i + 0][sxm] = xv[i].x;
            Xs[sxh + 4*i + 1][sxm] = xv[i].y;
            Xs[sxh + 4*i + 2][sxm] = xv[i].z;
            Xs[sxh + 4*i + 3][sxm] = xv[i].w;
            *(float4*)&Ws[swk][swc + 4*i] = wv[i];
        }
        __syncthreads();
        #pragma unroll 8
        for (int kk = 0; kk < 32; ++kk) {
            float4 a0 = *(const float4*)&Xs[kk][tm*8];
            float4 a1 = *(const float4*)&Xs[kk][tm*8 + 4];
            float4 b0 = *(const float4*)&Ws[kk][tn*8];
            float4 b1 = *(const float4*)&Ws[kk][tn*8 + 4];
            float av[8] = {a0.x,a0.y,a0.z,a0.w,a1.x,a1.y,a1.z,a1.w};
            float bw[8] = {b0.x,b0.y,b0.z,b0.w,b1.x,b1.y,b1.z,b1.w};
            #pragma unroll
            for (int i = 0; i < 8; ++i)
                #pragma unroll
                for (int j = 0; j < 8; ++j)
                    acc[i][j] = fmaf(av[i], bw[j], acc[i][j]);
        }
    }

    float4 bb0 = *(const float4*)&bias[nb + tn*8];
    float4 bb1 = *(const float4*)&bias[nb + tn*8 + 4];
    float bb[8] = {bb0.x,bb0.y,bb0.z,bb0.w,bb1.x,bb1.y,bb1.z,bb1.w};
    #pragma unroll
    for (int i = 0; i < 8; ++i) {
        const size_t row = (size_t)(mb + tm*8 + i);
        float4 o0 = {acc[i][0]+bb[0], acc[i][1]+bb[1], acc[i][2]+bb[2], acc[i][3]+bb[3]};
        float4 o1 = {acc[i][4]+bb[4], acc[i][5]+bb[5], acc[i][6]+bb[6], acc[i][7]+bb[7]};
        *(float4*)&Y[row*256 + nb + tn*8]     = o0;
        *(float4*)&Y[row*256 + nb + tn*8 + 4] = o1;
    }
}

// ---------------- RMSNorm rows in place (fp32) + bf16 copy (MFMA input) ----------------
__global__ __launch_bounds__(256)
void rmsnorm_rows(float* __restrict__ X, const float* __restrict__ g,
                  __hip_bfloat16* __restrict__ Xb)
{
    const int lane = threadIdx.x & 63;
    const size_t row = (size_t)blockIdx.x * 4 + (threadIdx.x >> 6);
    float4 x = *(const float4*)&X[row*256 + lane*4];
    float ssq = fmaf(x.x, x.x, fmaf(x.y, x.y, fmaf(x.z, x.z, x.w * x.w)));
    #pragma unroll
    for (int o = 1; o < 64; o <<= 1) ssq += __shfl_xor(ssq, o, 64);
    const float r = 1.0f / sqrtf(ssq * (1.0f/256.0f) + 1e-5f);
    float4 gg = *(const float4*)&g[lane*4];
    float y0 = (x.x*r)*gg.x, y1 = (x.y*r)*gg.y, y2 = (x.z*r)*gg.z, y3 = (x.w*r)*gg.w;
    float4 y = {y0, y1, y2, y3};
    *(float4*)&X[row*256 + lane*4] = y;
    __hip_bfloat16 h0 = __float2bfloat16(y0), h1 = __float2bfloat16(y1);
    __hip_bfloat16 h2 = __float2bfloat16(y2), h3 = __float2bfloat16(y3);
    ushort4 p;
    p.x = *(unsigned short*)&h0; p.y = *(unsigned short*)&h1;
    p.z = *(unsigned short*)&h2; p.w = *(unsigned short*)&h3;
    ((ushort4*)Xb)[row*64 + lane] = p;
}

// ---------------- bf16 MFMA logits: Out[32768][4096] = fp32(clamp(Q @ K^T * 1/16)) ----
// Direct-from-global fragments, no LDS, no barriers. 2x2 waves cover a 128x128 tile.
__global__ __launch_bounds__(256)
void mfma_logits(const __hip_bfloat16* __restrict__ Qb, const __hip_bfloat16* __restrict__ Kb,
                 float* __restrict__ Out)
{
    const int lane = threadIdx.x & 63;
    const int w  = threadIdx.x >> 6;
    const int wm = w >> 1, wn = w & 1;      // 2x2 wave grid of 64x64 quadrants
    const int mb = blockIdx.x * 128;
    const int nb = blockIdx.y * 128;
    const int fr = lane & 15;               // A row / B col within 16 fragment
    const int kg = (lane >> 4) * 8;         // k-group offset (guide §3 layout)

    f32x4 acc[4][4];
    #pragma unroll
    for (int mi = 0; mi < 4; ++mi)
        #pragma unroll
        for (int ni = 0; ni < 4; ++ni) {
            acc[mi][ni][0] = 0.f; acc[mi][ni][1] = 0.f;
            acc[mi][ni][2] = 0.f; acc[mi][ni][3] = 0.f;
        }

    const __hip_bfloat16* qbase = Qb + (size_t)(mb + wm*64 + fr) * 256 + kg;
    const __hip_bfloat16* kbase = Kb + (size_t)(nb + wn*64 + fr) * 256 + kg;

    #pragma unroll 2
    for (int k0 = 0; k0 < 256; k0 += 32) {
        bf16x8 af[4], bg[4];
        #pragma unroll
        for (int fi = 0; fi < 4; ++fi) {
            af[fi] = *(const bf16x8*)(qbase + (size_t)fi * 16 * 256 + k0);
            bg[fi] = *(const bf16x8*)(kbase + (size_t)fi * 16 * 256 + k0);
        }
        #pragma unroll
        for (int mi = 0; mi < 4; ++mi)
            #pragma unroll
            for (int ni = 0; ni < 4; ++ni)
                acc[mi][ni] = __builtin_amdgcn_mfma_f32_16x16x32_bf16(
                    af[mi], bg[ni], acc[mi][ni], 0, 0, 0);
    }

    // C/D layout: col = lane&15, row = (lane>>4)*4 + j  [guide §3, m89-verified]
    // Clamp to the mathematical bound |logit| <= 16 (RMS-normed rows: ||q||=||k||=16,
    // scale 1/16). No-op for correct values; NaN -> -16 via fmax-then-fmin ordering.
    const int cr = (lane >> 4) * 4;
    const int cc = lane & 15;
    #pragma unroll
    for (int mi = 0; mi < 4; ++mi)
        #pragma unroll
        for (int ni = 0; ni < 4; ++ni) {
            const size_t rb = (size_t)(mb + wm*64 + mi*16 + cr);
            const int col = nb + wn*64 + ni*16 + cc;
            #pragma unroll
            for (int j = 0; j < 4; ++j) {
                float v = acc[mi][ni][j] * 0.0625f;
                v = fminf(fmaxf(v, -16.0f), 16.0f);
                Out[(rb + j) * 4096 + col] = v;
            }
        }
}

// ---------------- FROZEN canonical fp32 dot (argmax determinism anchor) ----------------
// DO NOT change the summation structure in future rounds.
__device__ __forceinline__ float dot256_f32(const float* __restrict__ a, const float* __restrict__ b)
{
    float s0 = 0.f, s1 = 0.f, s2 = 0.f, s3 = 0.f;
    #pragma unroll 8
    for (int j = 0; j < 64; ++j) {
        float4 x = ((const float4*)a)[j];
        float4 y = ((const float4*)b)[j];
        s0 = fmaf(x.x, y.x, s0);
        s1 = fmaf(x.y, y.y, s1);
        s2 = fmaf(x.z, y.z, s2);
        s3 = fmaf(x.w, y.w, s3);
    }
    return (s0 + s1) + (s2 + s3);
}

// ---------------- refinement: candidates within MARGIN of row max, exact fp32 re-dot ----------------
// One wave per token row. Reads fp32 logits; margin 0.5 >> worst-case bf16-input MFMA
// error (~0.1), so the true fp32 argmax is provably among the candidates.
__global__ __launch_bounds__(256)
void refine_argmax(const float* __restrict__ L, const float* __restrict__ Qf,
                   const float* __restrict__ Kf, const float* __restrict__ Vf,
                   float* __restrict__ OutIdx, float* __restrict__ Zq,
                   float* __restrict__ Zq2)
{
    const int lane = threadIdx.x & 63;
    const size_t row = (size_t)blockIdx.x * 4 + (threadIdx.x >> 6);
    const float4* lrow = (const float4*)(L + row * 4096);

    float4 u[16];
    float vmax = -INFINITY;
    #pragma unroll
    for (int i = 0; i < 16; ++i) {
        u[i] = lrow[i*64 + lane];
        vmax = fmaxf(vmax, fmaxf(fmaxf(u[i].x, u[i].y), fmaxf(u[i].z, u[i].w)));
    }
    #pragma unroll
    for (int o = 1; o < 64; o <<= 1) vmax = fmaxf(vmax, __shfl_xor(vmax, o, 64));

    const float thr = vmax - 0.5f;
    float bv = -INFINITY;
    int   bi = 0;
    const float* qrow = Qf + row * 256;
    #pragma unroll
    for (int i = 0; i < 16; ++i) {
        const float* pe = (const float*)&u[i];
        #pragma unroll
        for (int e = 0; e < 4; ++e) {
            if (pe[e] >= thr) {
                const int c = (i*64 + lane)*4 + e;
                float rv = dot256_f32(qrow, Kf + (size_t)c * 256) * 0.0625f;
                if (rv > bv || (rv == bv && c < bi)) { bv = rv; bi = c; }
            }
        }
    }
    #pragma unroll
    for (int o = 1; o < 64; o <<= 1) {
        float ov = __shfl_xor(bv, o, 64);
        int   oi = __shfl_xor(bi, o, 64);
        if (ov > bv || (ov == bv && oi < bi)) { bv = ov; bi = oi; }
    }

    // safety clamp: never read OOB even on broken logits
    if (bi < 0) bi = 0;
    if (bi > 4095) bi = 4095;

    if (lane == 0) OutIdx[row] = (float)bi;   // idx as fp32 value in the fp32 out buffer

    // z_q = z_q_2 = v[idx]   (STE term cancels exactly in fp32: (0-s)+s == 0)
    float4 vv = ((const float4*)(Vf + (size_t)bi * 256))[lane];
    ((float4*)Zq)[row*64 + lane]  = vv;
    ((float4*)Zq2)[row*64 + lane] = vv;
}

extern "C" void kernel_launch(void* const* d_in, const int* in_sizes, int n_in,
                              void* d_out, int out_size, void* d_ws, size_t ws_size,
                              hipStream_t stream)
{
    (void)in_sizes; (void)n_in; (void)out_size;
    const float* hs = (const float*)d_in[0];
    const float* cb = (const float*)d_in[1];
    const float* wq = (const float*)d_in[2];
    const float* bq = (const float*)d_in[3];
    const float* wk = (const float*)d_in[4];
    const float* bk = (const float*)d_in[5];
    const float* wv = (const float*)d_in[6];
    const float* bv = (const float*)d_in[7];
    const float* gq = (const float*)d_in[8];
    const float* gk = (const float*)d_in[9];
    float* out = (float*)d_out;   // fp32: reference outputs are fp32/int32

    if (ws_size < 60817408u) return;  // need ~58 MB scratch; fail loudly if absent

    char* ws = (char*)d_ws;
    float* qf = (float*)ws;                                   // 32 MB: q raw -> q_norm (in place)
    float* kf = (float*)(ws + 33554432);                      //  4 MB: k raw -> k_norm (in place)
    float* vf = (float*)(ws + 37748736);                      //  4 MB: v
    __hip_bfloat16* qb = (__hip_bfloat16*)(ws + 41943040);    // 16 MB: q_norm bf16
    __hip_bfloat16* kb = (__hip_bfloat16*)(ws + 58720256);    //  2 MB: k_norm bf16

    gemm_xw256<<<dim3(32, 2),  256, 0, stream>>>(cb, wk, bk, kf);
    gemm_xw256<<<dim3(32, 2),  256, 0, stream>>>(cb, wv, bv, vf);
    gemm_xw256<<<dim3(256, 2), 256, 0, stream>>>(hs, wq, bq, qf);
    rmsnorm_rows<<<1024, 256, 0, stream>>>(kf, gk, kb);
    rmsnorm_rows<<<8192, 256, 0, stream>>>(qf, gq, qb);
    mfma_logits<<<dim3(256, 32), 256, 0, stream>>>(qb, kb, out);
    refine_argmax<<<8192, 256, 0, stream>>>(out, qf, kf, vf,
        out + 134217728ull,   // idx   [32768]
        out + 134250496ull,   // z_q   [32768*256]
        out + 142639104ull);  // z_q_2 [32768*256]
}

// Round 4
// 673.534 us; speedup vs baseline: 1.8489x; 1.8489x over previous
//
#include <hip/hip_runtime.h>
#include <hip/hip_bf16.h>

// AttentionForQuantizer: q/k/v proj + RMSNorm + logits(32768x4096) + argmax + gather.
// R4: refine_argmax restructured — LDS candidate compaction, then wave-PARALLEL
// frozen dots (one candidate per lane, single exec pass) instead of serialized
// exec-masked dots inside the scan loop. dot256_f32 is byte-identical (R3 passed
// with it; bit-identical rv -> identical argmax). mfma_logits/gemms/rmsnorm untouched.

#define NTOK 32768
#define NCODE 4096
#define DIM 256

typedef __bf16 bf16x8 __attribute__((ext_vector_type(8)));
typedef float f32x4 __attribute__((ext_vector_type(4)));

// ---------------- fp32 GEMM: Y[M][256] = X[M][256] @ W[256][256] + bias ----------------
// 128x128 tile per block, 256 threads, 8x8 per thread, BK=32.
__global__ __launch_bounds__(256, 2)
void gemm_xw256(const float* __restrict__ X, const float* __restrict__ W,
                const float* __restrict__ bias, float* __restrict__ Y)
{
    __shared__ __align__(16) float Xs[32][132];  // [kk][m], padded
    __shared__ __align__(16) float Ws[32][132];  // [kk][n], padded
    const int t  = threadIdx.x;
    const int tm = t >> 4;         // 0..15
    const int tn = t & 15;         // 0..15
    const int mb = blockIdx.x * 128;
    const int nb = blockIdx.y * 128;

    float acc[8][8];
    #pragma unroll
    for (int i = 0; i < 8; ++i)
        #pragma unroll
        for (int j = 0; j < 8; ++j) acc[i][j] = 0.f;

    const int sxm = t >> 1;          // X staging: row 0..127
    const int sxh = (t & 1) * 16;    // X staging: k-half base
    const int swk = t >> 3;          // W staging: kk 0..31
    const int swc = (t & 7) * 16;    // W staging: col base

    for (int kb = 0; kb < 256; kb += 32) {
        float4 xv[4], wv[4];
        #pragma unroll
        for (int i = 0; i < 4; ++i) {
            xv[i] = *(const float4*)&X[(size_t)(mb + sxm) * 256 + kb + sxh + 4 * i];
            wv[i] = *(const float4*)&W[(size_t)(kb + swk) * 256 + nb + swc + 4 * i];
        }
        __syncthreads();  // previous iteration's LDS reads done before overwrite
        #pragma unroll
        for (int i = 0; i < 4; ++i) {
            Xs[sxh + 4*i + 0][sxm] = xv[i].x;
            Xs[sxh + 4*i + 1][sxm] = xv[i].y;
            Xs[sxh + 4*i + 2][sxm] = xv[i].z;
            Xs[sxh + 4*i + 3][sxm] = xv[i].w;
            *(float4*)&Ws[swk][swc + 4*i] = wv[i];
        }
        __syncthreads();
        #pragma unroll 8
        for (int kk = 0; kk < 32; ++kk) {
            float4 a0 = *(const float4*)&Xs[kk][tm*8];
            float4 a1 = *(const float4*)&Xs[kk][tm*8 + 4];
            float4 b0 = *(const float4*)&Ws[kk][tn*8];
            float4 b1 = *(const float4*)&Ws[kk][tn*8 + 4];
            float av[8] = {a0.x,a0.y,a0.z,a0.w,a1.x,a1.y,a1.z,a1.w};
            float bw[8] = {b0.x,b0.y,b0.z,b0.w,b1.x,b1.y,b1.z,b1.w};
            #pragma unroll
            for (int i = 0; i < 8; ++i)
                #pragma unroll
                for (int j = 0; j < 8; ++j)
                    acc[i][j] = fmaf(av[i], bw[j], acc[i][j]);
        }
    }

    float4 bb0 = *(const float4*)&bias[nb + tn*8];
    float4 bb1 = *(const float4*)&bias[nb + tn*8 + 4];
    float bb[8] = {bb0.x,bb0.y,bb0.z,bb0.w,bb1.x,bb1.y,bb1.z,bb1.w};
    #pragma unroll
    for (int i = 0; i < 8; ++i) {
        const size_t row = (size_t)(mb + tm*8 + i);
        float4 o0 = {acc[i][0]+bb[0], acc[i][1]+bb[1], acc[i][2]+bb[2], acc[i][3]+bb[3]};
        float4 o1 = {acc[i][4]+bb[4], acc[i][5]+bb[5], acc[i][6]+bb[6], acc[i][7]+bb[7]};
        *(float4*)&Y[row*256 + nb + tn*8]     = o0;
        *(float4*)&Y[row*256 + nb + tn*8 + 4] = o1;
    }
}

// ---------------- RMSNorm rows in place (fp32) + bf16 copy (MFMA input) ----------------
__global__ __launch_bounds__(256)
void rmsnorm_rows(float* __restrict__ X, const float* __restrict__ g,
                  __hip_bfloat16* __restrict__ Xb)
{
    const int lane = threadIdx.x & 63;
    const size_t row = (size_t)blockIdx.x * 4 + (threadIdx.x >> 6);
    float4 x = *(const float4*)&X[row*256 + lane*4];
    float ssq = fmaf(x.x, x.x, fmaf(x.y, x.y, fmaf(x.z, x.z, x.w * x.w)));
    #pragma unroll
    for (int o = 1; o < 64; o <<= 1) ssq += __shfl_xor(ssq, o, 64);
    const float r = 1.0f / sqrtf(ssq * (1.0f/256.0f) + 1e-5f);
    float4 gg = *(const float4*)&g[lane*4];
    float y0 = (x.x*r)*gg.x, y1 = (x.y*r)*gg.y, y2 = (x.z*r)*gg.z, y3 = (x.w*r)*gg.w;
    float4 y = {y0, y1, y2, y3};
    *(float4*)&X[row*256 + lane*4] = y;
    __hip_bfloat16 h0 = __float2bfloat16(y0), h1 = __float2bfloat16(y1);
    __hip_bfloat16 h2 = __float2bfloat16(y2), h3 = __float2bfloat16(y3);
    ushort4 p;
    p.x = *(unsigned short*)&h0; p.y = *(unsigned short*)&h1;
    p.z = *(unsigned short*)&h2; p.w = *(unsigned short*)&h3;
    ((ushort4*)Xb)[row*64 + lane] = p;
}

// ---------------- bf16 MFMA logits: Out[32768][4096] = fp32(clamp(Q @ K^T * 1/16)) ----
// Direct-from-global fragments, no LDS, no barriers. 2x2 waves cover a 128x128 tile.
__global__ __launch_bounds__(256)
void mfma_logits(const __hip_bfloat16* __restrict__ Qb, const __hip_bfloat16* __restrict__ Kb,
                 float* __restrict__ Out)
{
    const int lane = threadIdx.x & 63;
    const int w  = threadIdx.x >> 6;
    const int wm = w >> 1, wn = w & 1;      // 2x2 wave grid of 64x64 quadrants
    const int mb = blockIdx.x * 128;
    const int nb = blockIdx.y * 128;
    const int fr = lane & 15;               // A row / B col within 16 fragment
    const int kg = (lane >> 4) * 8;         // k-group offset (guide §3 layout)

    f32x4 acc[4][4];
    #pragma unroll
    for (int mi = 0; mi < 4; ++mi)
        #pragma unroll
        for (int ni = 0; ni < 4; ++ni) {
            acc[mi][ni][0] = 0.f; acc[mi][ni][1] = 0.f;
            acc[mi][ni][2] = 0.f; acc[mi][ni][3] = 0.f;
        }

    const __hip_bfloat16* qbase = Qb + (size_t)(mb + wm*64 + fr) * 256 + kg;
    const __hip_bfloat16* kbase = Kb + (size_t)(nb + wn*64 + fr) * 256 + kg;

    #pragma unroll 2
    for (int k0 = 0; k0 < 256; k0 += 32) {
        bf16x8 af[4], bg[4];
        #pragma unroll
        for (int fi = 0; fi < 4; ++fi) {
            af[fi] = *(const bf16x8*)(qbase + (size_t)fi * 16 * 256 + k0);
            bg[fi] = *(const bf16x8*)(kbase + (size_t)fi * 16 * 256 + k0);
        }
        #pragma unroll
        for (int mi = 0; mi < 4; ++mi)
            #pragma unroll
            for (int ni = 0; ni < 4; ++ni)
                acc[mi][ni] = __builtin_amdgcn_mfma_f32_16x16x32_bf16(
                    af[mi], bg[ni], acc[mi][ni], 0, 0, 0);
    }

    // C/D layout: col = lane&15, row = (lane>>4)*4 + j  [guide §3, m89-verified]
    // Clamp to the mathematical bound |logit| <= 16 (RMS-normed rows: ||q||=||k||=16,
    // scale 1/16). No-op for correct values; NaN -> -16 via fmax-then-fmin ordering.
    const int cr = (lane >> 4) * 4;
    const int cc = lane & 15;
    #pragma unroll
    for (int mi = 0; mi < 4; ++mi)
        #pragma unroll
        for (int ni = 0; ni < 4; ++ni) {
            const size_t rb = (size_t)(mb + wm*64 + mi*16 + cr);
            const int col = nb + wn*64 + ni*16 + cc;
            #pragma unroll
            for (int j = 0; j < 4; ++j) {
                float v = acc[mi][ni][j] * 0.0625f;
                v = fminf(fmaxf(v, -16.0f), 16.0f);
                Out[(rb + j) * 4096 + col] = v;
            }
        }
}

// ---------------- FROZEN canonical fp32 dot (argmax determinism anchor) ----------------
// DO NOT change the summation structure in future rounds. R3 PASSED with this exact
// sequence (0 argmax flips vs numpy on the fixed dataset) — it must stay bit-identical.
__device__ __forceinline__ float dot256_f32(const float* __restrict__ a, const float* __restrict__ b)
{
    float s0 = 0.f, s1 = 0.f, s2 = 0.f, s3 = 0.f;
    #pragma unroll 8
    for (int j = 0; j < 64; ++j) {
        float4 x = ((const float4*)a)[j];
        float4 y = ((const float4*)b)[j];
        s0 = fmaf(x.x, y.x, s0);
        s1 = fmaf(x.y, y.y, s1);
        s2 = fmaf(x.z, y.z, s2);
        s3 = fmaf(x.w, y.w, s3);
    }
    return (s0 + s1) + (s2 + s3);
}

// ---------------- refinement: compact candidates, then wave-parallel frozen dots ------
// One wave per token row. Candidates (logit >= rowmax - 0.5; margin >> bf16-MFMA error
// ~0.1 so the true fp32 argmax is provably included) are compacted into an LDS list,
// then dispatched ONE PER LANE in a single exec pass — same dot256_f32 per candidate,
// bit-identical values; max-with-min-idx-tiebreak reduce is order-independent.
__global__ __launch_bounds__(256)
void refine_argmax(const float* __restrict__ L, const float* __restrict__ Qf,
                   const float* __restrict__ Kf, const float* __restrict__ Vf,
                   float* __restrict__ OutIdx, float* __restrict__ Zq,
                   float* __restrict__ Zq2)
{
    __shared__ int cnt[4];
    __shared__ int list[4][256];
    const int lane = threadIdx.x & 63;
    const int w    = threadIdx.x >> 6;
    const size_t row = (size_t)blockIdx.x * 4 + w;
    const float4* lrow = (const float4*)(L + row * 4096);

    // phase 1: coalesced row read + row max
    float4 u[16];
    float vmax = -INFINITY;
    #pragma unroll
    for (int i = 0; i < 16; ++i) {
        u[i] = lrow[i*64 + lane];
        vmax = fmaxf(vmax, fmaxf(fmaxf(u[i].x, u[i].y), fmaxf(u[i].z, u[i].w)));
    }
    #pragma unroll
    for (int o = 1; o < 64; o <<= 1) vmax = fmaxf(vmax, __shfl_xor(vmax, o, 64));

    if (lane == 0) cnt[w] = 0;
    __syncthreads();   // unconditional: every thread reaches this

    // phase 2: candidate compaction (no dots here — cheap VALU + rare LDS atomics)
    const float thr = vmax - 0.5f;
    #pragma unroll
    for (int i = 0; i < 16; ++i) {
        const float* pe = (const float*)&u[i];
        #pragma unroll
        for (int e = 0; e < 4; ++e) {
            if (pe[e] >= thr) {
                int slot = atomicAdd(&cnt[w], 1);
                if (slot < 256) list[w][slot] = (i*64 + lane)*4 + e;
            }
        }
    }
    __syncthreads();   // unconditional

    // phase 3: one candidate per lane, all dots in ONE exec pass
    int m = cnt[w]; if (m > 256) m = 256;   // P(overflow) ~ 0 for this fixed dataset
    float bv = -INFINITY;
    int   bi = 0x7fffffff;
    const float* qrow = Qf + row * 256;
    for (int base = 0; base < m; base += 64) {
        const int ci = base + lane;
        if (ci < m) {
            const int c = list[w][ci];
            float rv = dot256_f32(qrow, Kf + (size_t)c * 256) * 0.0625f;
            if (rv > bv || (rv == bv && c < bi)) { bv = rv; bi = c; }
        }
    }
    #pragma unroll
    for (int o = 1; o < 64; o <<= 1) {
        float ov = __shfl_xor(bv, o, 64);
        int   oi = __shfl_xor(bi, o, 64);
        if (ov > bv || (ov == bv && oi < bi)) { bv = ov; bi = oi; }
    }

    // safety clamp: never read OOB even on broken logits
    if (bi < 0) bi = 0;
    if (bi > 4095) bi = 4095;

    if (lane == 0) OutIdx[row] = (float)bi;   // idx as fp32 value in the fp32 out buffer

    // z_q = z_q_2 = v[idx]   (STE term cancels exactly in fp32: (0-s)+s == 0)
    float4 vv = ((const float4*)(Vf + (size_t)bi * 256))[lane];
    ((float4*)Zq)[row*64 + lane]  = vv;
    ((float4*)Zq2)[row*64 + lane] = vv;
}

extern "C" void kernel_launch(void* const* d_in, const int* in_sizes, int n_in,
                              void* d_out, int out_size, void* d_ws, size_t ws_size,
                              hipStream_t stream)
{
    (void)in_sizes; (void)n_in; (void)out_size;
    const float* hs = (const float*)d_in[0];
    const float* cb = (const float*)d_in[1];
    const float* wq = (const float*)d_in[2];
    const float* bq = (const float*)d_in[3];
    const float* wk = (const float*)d_in[4];
    const float* bk = (const float*)d_in[5];
    const float* wv = (const float*)d_in[6];
    const float* bv = (const float*)d_in[7];
    const float* gq = (const float*)d_in[8];
    const float* gk = (const float*)d_in[9];
    float* out = (float*)d_out;   // fp32: reference outputs are fp32/int32

    if (ws_size < 60817408u) return;  // need ~58 MB scratch; fail loudly if absent

    char* ws = (char*)d_ws;
    float* qf = (float*)ws;                                   // 32 MB: q raw -> q_norm (in place)
    float* kf = (float*)(ws + 33554432);                      //  4 MB: k raw -> k_norm (in place)
    float* vf = (float*)(ws + 37748736);                      //  4 MB: v
    __hip_bfloat16* qb = (__hip_bfloat16*)(ws + 41943040);    // 16 MB: q_norm bf16
    __hip_bfloat16* kb = (__hip_bfloat16*)(ws + 58720256);    //  2 MB: k_norm bf16

    gemm_xw256<<<dim3(32, 2),  256, 0, stream>>>(cb, wk, bk, kf);
    gemm_xw256<<<dim3(32, 2),  256, 0, stream>>>(cb, wv, bv, vf);
    gemm_xw256<<<dim3(256, 2), 256, 0, stream>>>(hs, wq, bq, qf);
    rmsnorm_rows<<<1024, 256, 0, stream>>>(kf, gk, kb);
    rmsnorm_rows<<<8192, 256, 0, stream>>>(qf, gq, qb);
    mfma_logits<<<dim3(256, 32), 256, 0, stream>>>(qb, kb, out);
    refine_argmax<<<8192, 256, 0, stream>>>(out, qf, kf, vf,
        out + 134217728ull,   // idx   [32768]
        out + 134250496ull,   // z_q   [32768*256]
        out + 142639104ull);  // z_q_2 [32768*256]
}

// Round 5
// 560.316 us; speedup vs baseline: 2.2224x; 1.2021x over previous
//
#include <hip/hip_runtime.h>
#include <hip/hip_bf16.h>

// AttentionForQuantizer: q/k/v proj + RMSNorm + logits(32768x4096) + argmax + gather.
// R5: mfma_logits rewritten in the m97 structure — 128^2 tile, BK=64, global_load_lds
// width-16 staging (R1's staging was never actually broken; R1/R2 failures were the
// d_out dtype misread), LDS XOR-swizzle done both-sides (linear LDS dest, pre-swizzled
// global source slot ^= row&7, swizzled ds_read). MFMA k-order ascending 0,32,..,224 —
// bit-identical accumulation to the R4 passing kernel. refine/gemms/rmsnorm untouched.

#define NTOK 32768
#define NCODE 4096
#define DIM 256

typedef __bf16 bf16x8 __attribute__((ext_vector_type(8)));
typedef float f32x4 __attribute__((ext_vector_type(4)));

// ---------------- fp32 GEMM: Y[M][256] = X[M][256] @ W[256][256] + bias ----------------
// 128x128 tile per block, 256 threads, 8x8 per thread, BK=32.
__global__ __launch_bounds__(256, 2)
void gemm_xw256(const float* __restrict__ X, const float* __restrict__ W,
                const float* __restrict__ bias, float* __restrict__ Y)
{
    __shared__ __align__(16) float Xs[32][132];  // [kk][m], padded
    __shared__ __align__(16) float Ws[32][132];  // [kk][n], padded
    const int t  = threadIdx.x;
    const int tm = t >> 4;         // 0..15
    const int tn = t & 15;         // 0..15
    const int mb = blockIdx.x * 128;
    const int nb = blockIdx.y * 128;

    float acc[8][8];
    #pragma unroll
    for (int i = 0; i < 8; ++i)
        #pragma unroll
        for (int j = 0; j < 8; ++j) acc[i][j] = 0.f;

    const int sxm = t >> 1;          // X staging: row 0..127
    const int sxh = (t & 1) * 16;    // X staging: k-half base
    const int swk = t >> 3;          // W staging: kk 0..31
    const int swc = (t & 7) * 16;    // W staging: col base

    for (int kb = 0; kb < 256; kb += 32) {
        float4 xv[4], wv[4];
        #pragma unroll
        for (int i = 0; i < 4; ++i) {
            xv[i] = *(const float4*)&X[(size_t)(mb + sxm) * 256 + kb + sxh + 4 * i];
            wv[i] = *(const float4*)&W[(size_t)(kb + swk) * 256 + nb + swc + 4 * i];
        }
        __syncthreads();  // previous iteration's LDS reads done before overwrite
        #pragma unroll
        for (int i = 0; i < 4; ++i) {
            Xs[sxh + 4*i + 0][sxm] = xv[i].x;
            Xs[sxh + 4*i + 1][sxm] = xv[i].y;
            Xs[sxh + 4*i + 2][sxm] = xv[i].z;
            Xs[sxh + 4*i + 3][sxm] = xv[i].w;
            *(float4*)&Ws[swk][swc + 4*i] = wv[i];
        }
        __syncthreads();
        #pragma unroll 8
        for (int kk = 0; kk < 32; ++kk) {
            float4 a0 = *(const float4*)&Xs[kk][tm*8];
            float4 a1 = *(const float4*)&Xs[kk][tm*8 + 4];
            float4 b0 = *(const float4*)&Ws[kk][tn*8];
            float4 b1 = *(const float4*)&Ws[kk][tn*8 + 4];
            float av[8] = {a0.x,a0.y,a0.z,a0.w,a1.x,a1.y,a1.z,a1.w};
            float bw[8] = {b0.x,b0.y,b0.z,b0.w,b1.x,b1.y,b1.z,b1.w};
            #pragma unroll
            for (int i = 0; i < 8; ++i)
                #pragma unroll
                for (int j = 0; j < 8; ++j)
                    acc[i][j] = fmaf(av[i], bw[j], acc[i][j]);
        }
    }

    float4 bb0 = *(const float4*)&bias[nb + tn*8];
    float4 bb1 = *(const float4*)&bias[nb + tn*8 + 4];
    float bb[8] = {bb0.x,bb0.y,bb0.z,bb0.w,bb1.x,bb1.y,bb1.z,bb1.w};
    #pragma unroll
    for (int i = 0; i < 8; ++i) {
        const size_t row = (size_t)(mb + tm*8 + i);
        float4 o0 = {acc[i][0]+bb[0], acc[i][1]+bb[1], acc[i][2]+bb[2], acc[i][3]+bb[3]};
        float4 o1 = {acc[i][4]+bb[4], acc[i][5]+bb[5], acc[i][6]+bb[6], acc[i][7]+bb[7]};
        *(float4*)&Y[row*256 + nb + tn*8]     = o0;
        *(float4*)&Y[row*256 + nb + tn*8 + 4] = o1;
    }
}

// ---------------- RMSNorm rows in place (fp32) + bf16 copy (MFMA input) ----------------
__global__ __launch_bounds__(256)
void rmsnorm_rows(float* __restrict__ X, const float* __restrict__ g,
                  __hip_bfloat16* __restrict__ Xb)
{
    const int lane = threadIdx.x & 63;
    const size_t row = (size_t)blockIdx.x * 4 + (threadIdx.x >> 6);
    float4 x = *(const float4*)&X[row*256 + lane*4];
    float ssq = fmaf(x.x, x.x, fmaf(x.y, x.y, fmaf(x.z, x.z, x.w * x.w)));
    #pragma unroll
    for (int o = 1; o < 64; o <<= 1) ssq += __shfl_xor(ssq, o, 64);
    const float r = 1.0f / sqrtf(ssq * (1.0f/256.0f) + 1e-5f);
    float4 gg = *(const float4*)&g[lane*4];
    float y0 = (x.x*r)*gg.x, y1 = (x.y*r)*gg.y, y2 = (x.z*r)*gg.z, y3 = (x.w*r)*gg.w;
    float4 y = {y0, y1, y2, y3};
    *(float4*)&X[row*256 + lane*4] = y;
    __hip_bfloat16 h0 = __float2bfloat16(y0), h1 = __float2bfloat16(y1);
    __hip_bfloat16 h2 = __float2bfloat16(y2), h3 = __float2bfloat16(y3);
    ushort4 p;
    p.x = *(unsigned short*)&h0; p.y = *(unsigned short*)&h1;
    p.z = *(unsigned short*)&h2; p.w = *(unsigned short*)&h3;
    ((ushort4*)Xb)[row*64 + lane] = p;
}

// ---------------- bf16 MFMA logits: Out[32768][4096] = fp32(clamp(Q @ K^T * 1/16)) ----
// m97 structure: 128x128 tile, BK=64, global_load_lds(16B) staging, 2 barriers/K-step.
// Swizzle (rule #21, both-sides): LDS dest linear; global SOURCE slot pre-permuted by
// the involution slot^=row&7; ds_read applies the same XOR -> conflict-free b128 reads.
__device__ __forceinline__ void load_lds16(const void* g, void* l) {
    __builtin_amdgcn_global_load_lds((const __attribute__((address_space(1))) unsigned int*)g,
                                     (__attribute__((address_space(3))) unsigned int*)l, 16, 0, 0);
}

__global__ __launch_bounds__(256, 2)
void mfma_logits(const __hip_bfloat16* __restrict__ Qb, const __hip_bfloat16* __restrict__ Kb,
                 float* __restrict__ Out)
{
    // [128 rows][64 k] bf16, 16 KB each; row = 8 slots of 16B, slot content swizzled.
    __shared__ __align__(16) __hip_bfloat16 Asm[128 * 64];
    __shared__ __align__(16) __hip_bfloat16 Bsm[128 * 64];

    const int t    = threadIdx.x;
    const int lane = t & 63;
    const int w    = t >> 6;
    const int wm = w >> 1, wn = w & 1;      // 2x2 wave grid of 64x64 quadrants
    const int mb = blockIdx.x * 128;
    const int nb = blockIdx.y * 128;

    // --- staging geometry: chunk c = i*256 + t; row = i*32 + (t>>3); within-row slot
    // written at (t&7) holds global slot (t&7)^((t>>3)&7)  [involution, row-local] ---
    const int grow   = t >> 3;                       // + i*32 per issue
    const int gslot  = (t & 7) ^ ((t >> 3) & 7);
    const __hip_bfloat16* gA = Qb + (size_t)(mb + grow) * 256 + gslot * 8;
    const __hip_bfloat16* gB = Kb + (size_t)(nb + grow) * 256 + gslot * 8;
    __hip_bfloat16* lA = &Asm[w * 512];              // + i*2048 per issue (bf16 elems)
    __hip_bfloat16* lB = &Bsm[w * 512];

    // --- fragment geometry (guide §3): fr = lane&15 row-in-16, kq = lane>>4 ---
    const int fr = lane & 15;
    const int kq = lane >> 4;
    const int rswz = lane & 7;                       // row&7 for all our fragment rows
    const int ra0 = (wm * 64 + fr) * 64;             // A base elem offset (row*64)
    const int rb0 = (wn * 64 + fr) * 64;

    f32x4 acc[4][4];
    #pragma unroll
    for (int mi = 0; mi < 4; ++mi)
        #pragma unroll
        for (int ni = 0; ni < 4; ++ni) {
            acc[mi][ni][0] = 0.f; acc[mi][ni][1] = 0.f;
            acc[mi][ni][2] = 0.f; acc[mi][ni][3] = 0.f;
        }

    for (int ks = 0; ks < 4; ++ks) {
        const int k0 = ks * 64;
        #pragma unroll
        for (int i = 0; i < 4; ++i) {
            load_lds16(gA + (size_t)i * 32 * 256 + k0, lA + i * 2048);
            load_lds16(gB + (size_t)i * 32 * 256 + k0, lB + i * 2048);
        }
        __syncthreads();   // compiler drains vmcnt(0) before s_barrier [m97 evidence]

        #pragma unroll
        for (int kh = 0; kh < 2; ++kh) {            // k = ks*64 + kh*32 (ascending ==
            bf16x8 af[4], bg[4];                    //  R4's order -> bit-identical acc)
            #pragma unroll
            for (int mi = 0; mi < 4; ++mi)
                af[mi] = *(const bf16x8*)&Asm[ra0 + mi*16*64 + (((kh<<2) + kq) ^ rswz) * 8];
            #pragma unroll
            for (int ni = 0; ni < 4; ++ni)
                bg[ni] = *(const bf16x8*)&Bsm[rb0 + ni*16*64 + (((kh<<2) + kq) ^ rswz) * 8];
            #pragma unroll
            for (int mi = 0; mi < 4; ++mi)
                #pragma unroll
                for (int ni = 0; ni < 4; ++ni)
                    acc[mi][ni] = __builtin_amdgcn_mfma_f32_16x16x32_bf16(
                        af[mi], bg[ni], acc[mi][ni], 0, 0, 0);
        }
        __syncthreads();   // LDS reads done before next K-step overwrites
    }

    // C/D layout: col = lane&15, row = (lane>>4)*4 + j  [guide §3, m89-verified]
    // Clamp to the mathematical bound |logit| <= 16 (RMS-normed rows: ||q||=||k||=16,
    // scale 1/16). No-op for correct values; NaN -> -16 via fmax-then-fmin ordering.
    const int cr = (lane >> 4) * 4;
    const int cc = lane & 15;
    #pragma unroll
    for (int mi = 0; mi < 4; ++mi)
        #pragma unroll
        for (int ni = 0; ni < 4; ++ni) {
            const size_t rb = (size_t)(mb + wm*64 + mi*16 + cr);
            const int col = nb + wn*64 + ni*16 + cc;
            #pragma unroll
            for (int j = 0; j < 4; ++j) {
                float v = acc[mi][ni][j] * 0.0625f;
                v = fminf(fmaxf(v, -16.0f), 16.0f);
                Out[(rb + j) * 4096 + col] = v;
            }
        }
}

// ---------------- FROZEN canonical fp32 dot (argmax determinism anchor) ----------------
// DO NOT change the summation structure in future rounds. R3/R4 PASSED with this exact
// sequence (0 argmax flips vs numpy on the fixed dataset) — it must stay bit-identical.
__device__ __forceinline__ float dot256_f32(const float* __restrict__ a, const float* __restrict__ b)
{
    float s0 = 0.f, s1 = 0.f, s2 = 0.f, s3 = 0.f;
    #pragma unroll 8
    for (int j = 0; j < 64; ++j) {
        float4 x = ((const float4*)a)[j];
        float4 y = ((const float4*)b)[j];
        s0 = fmaf(x.x, y.x, s0);
        s1 = fmaf(x.y, y.y, s1);
        s2 = fmaf(x.z, y.z, s2);
        s3 = fmaf(x.w, y.w, s3);
    }
    return (s0 + s1) + (s2 + s3);
}

// ---------------- refinement: compact candidates, then wave-parallel frozen dots ------
// One wave per token row. Candidates (logit >= rowmax - 0.5; margin >> bf16-MFMA error
// ~0.1 so the true fp32 argmax is provably included) are compacted into an LDS list,
// then dispatched ONE PER LANE in a single exec pass — same dot256_f32 per candidate,
// bit-identical values; max-with-min-idx-tiebreak reduce is order-independent.
__global__ __launch_bounds__(256)
void refine_argmax(const float* __restrict__ L, const float* __restrict__ Qf,
                   const float* __restrict__ Kf, const float* __restrict__ Vf,
                   float* __restrict__ OutIdx, float* __restrict__ Zq,
                   float* __restrict__ Zq2)
{
    __shared__ int cnt[4];
    __shared__ int list[4][256];
    const int lane = threadIdx.x & 63;
    const int w    = threadIdx.x >> 6;
    const size_t row = (size_t)blockIdx.x * 4 + w;
    const float4* lrow = (const float4*)(L + row * 4096);

    // phase 1: coalesced row read + row max
    float4 u[16];
    float vmax = -INFINITY;
    #pragma unroll
    for (int i = 0; i < 16; ++i) {
        u[i] = lrow[i*64 + lane];
        vmax = fmaxf(vmax, fmaxf(fmaxf(u[i].x, u[i].y), fmaxf(u[i].z, u[i].w)));
    }
    #pragma unroll
    for (int o = 1; o < 64; o <<= 1) vmax = fmaxf(vmax, __shfl_xor(vmax, o, 64));

    if (lane == 0) cnt[w] = 0;
    __syncthreads();   // unconditional: every thread reaches this

    // phase 2: candidate compaction (no dots here — cheap VALU + rare LDS atomics)
    const float thr = vmax - 0.5f;
    #pragma unroll
    for (int i = 0; i < 16; ++i) {
        const float* pe = (const float*)&u[i];
        #pragma unroll
        for (int e = 0; e < 4; ++e) {
            if (pe[e] >= thr) {
                int slot = atomicAdd(&cnt[w], 1);
                if (slot < 256) list[w][slot] = (i*64 + lane)*4 + e;
            }
        }
    }
    __syncthreads();   // unconditional

    // phase 3: one candidate per lane, all dots in ONE exec pass
    int m = cnt[w]; if (m > 256) m = 256;   // P(overflow) ~ 0 for this fixed dataset
    float bv = -INFINITY;
    int   bi = 0x7fffffff;
    const float* qrow = Qf + row * 256;
    for (int base = 0; base < m; base += 64) {
        const int ci = base + lane;
        if (ci < m) {
            const int c = list[w][ci];
            float rv = dot256_f32(qrow, Kf + (size_t)c * 256) * 0.0625f;
            if (rv > bv || (rv == bv && c < bi)) { bv = rv; bi = c; }
        }
    }
    #pragma unroll
    for (int o = 1; o < 64; o <<= 1) {
        float ov = __shfl_xor(bv, o, 64);
        int   oi = __shfl_xor(bi, o, 64);
        if (ov > bv || (ov == bv && oi < bi)) { bv = ov; bi = oi; }
    }

    // safety clamp: never read OOB even on broken logits
    if (bi < 0) bi = 0;
    if (bi > 4095) bi = 4095;

    if (lane == 0) OutIdx[row] = (float)bi;   // idx as fp32 value in the fp32 out buffer

    // z_q = z_q_2 = v[idx]   (STE term cancels exactly in fp32: (0-s)+s == 0)
    float4 vv = ((const float4*)(Vf + (size_t)bi * 256))[lane];
    ((float4*)Zq)[row*64 + lane]  = vv;
    ((float4*)Zq2)[row*64 + lane] = vv;
}

extern "C" void kernel_launch(void* const* d_in, const int* in_sizes, int n_in,
                              void* d_out, int out_size, void* d_ws, size_t ws_size,
                              hipStream_t stream)
{
    (void)in_sizes; (void)n_in; (void)out_size;
    const float* hs = (const float*)d_in[0];
    const float* cb = (const float*)d_in[1];
    const float* wq = (const float*)d_in[2];
    const float* bq = (const float*)d_in[3];
    const float* wk = (const float*)d_in[4];
    const float* bk = (const float*)d_in[5];
    const float* wv = (const float*)d_in[6];
    const float* bv = (const float*)d_in[7];
    const float* gq = (const float*)d_in[8];
    const float* gk = (const float*)d_in[9];
    float* out = (float*)d_out;   // fp32: reference outputs are fp32/int32

    if (ws_size < 60817408u) return;  // need ~58 MB scratch; fail loudly if absent

    char* ws = (char*)d_ws;
    float* qf = (float*)ws;                                   // 32 MB: q raw -> q_norm (in place)
    float* kf = (float*)(ws + 33554432);                      //  4 MB: k raw -> k_norm (in place)
    float* vf = (float*)(ws + 37748736);                      //  4 MB: v
    __hip_bfloat16* qb = (__hip_bfloat16*)(ws + 41943040);    // 16 MB: q_norm bf16
    __hip_bfloat16* kb = (__hip_bfloat16*)(ws + 58720256);    //  2 MB: k_norm bf16

    gemm_xw256<<<dim3(32, 2),  256, 0, stream>>>(cb, wk, bk, kf);
    gemm_xw256<<<dim3(32, 2),  256, 0, stream>>>(cb, wv, bv, vf);
    gemm_xw256<<<dim3(256, 2), 256, 0, stream>>>(hs, wq, bq, qf);
    rmsnorm_rows<<<1024, 256, 0, stream>>>(kf, gk, kb);
    rmsnorm_rows<<<8192, 256, 0, stream>>>(qf, gq, qb);
    mfma_logits<<<dim3(256, 32), 256, 0, stream>>>(qb, kb, out);
    refine_argmax<<<8192, 256, 0, stream>>>(out, qf, kf, vf,
        out + 134217728ull,   // idx   [32768]
        out + 134250496ull,   // z_q   [32768*256]
        out + 142639104ull);  // z_q_2 [32768*256]
}

// Round 6
// 542.115 us; speedup vs baseline: 2.2971x; 1.0336x over previous
//
#include <hip/hip_runtime.h>
#include <hip/hip_bf16.h>

// AttentionForQuantizer: q/k/v proj + RMSNorm + logits(32768x4096) + argmax + gather.
// R6: mfma_logits epilogue rewritten — LDS-bounce transpose so global stores are
// full-row dwordx4 (was: 64 scalar dword stores/thread at 64B/row segments, ~2.4TB/s
// effective). Values bit-identical (same clamp(acc*0.0625) ops, same order; only the
// store path changed). Main loop / refine / gemms / rmsnorm untouched from R5 (passed).

#define NTOK 32768
#define NCODE 4096
#define DIM 256

typedef __bf16 bf16x8 __attribute__((ext_vector_type(8)));
typedef float f32x4 __attribute__((ext_vector_type(4)));

// ---------------- fp32 GEMM: Y[M][256] = X[M][256] @ W[256][256] + bias ----------------
// 128x128 tile per block, 256 threads, 8x8 per thread, BK=32.
__global__ __launch_bounds__(256, 2)
void gemm_xw256(const float* __restrict__ X, const float* __restrict__ W,
                const float* __restrict__ bias, float* __restrict__ Y)
{
    __shared__ __align__(16) float Xs[32][132];  // [kk][m], padded
    __shared__ __align__(16) float Ws[32][132];  // [kk][n], padded
    const int t  = threadIdx.x;
    const int tm = t >> 4;         // 0..15
    const int tn = t & 15;         // 0..15
    const int mb = blockIdx.x * 128;
    const int nb = blockIdx.y * 128;

    float acc[8][8];
    #pragma unroll
    for (int i = 0; i < 8; ++i)
        #pragma unroll
        for (int j = 0; j < 8; ++j) acc[i][j] = 0.f;

    const int sxm = t >> 1;          // X staging: row 0..127
    const int sxh = (t & 1) * 16;    // X staging: k-half base
    const int swk = t >> 3;          // W staging: kk 0..31
    const int swc = (t & 7) * 16;    // W staging: col base

    for (int kb = 0; kb < 256; kb += 32) {
        float4 xv[4], wv[4];
        #pragma unroll
        for (int i = 0; i < 4; ++i) {
            xv[i] = *(const float4*)&X[(size_t)(mb + sxm) * 256 + kb + sxh + 4 * i];
            wv[i] = *(const float4*)&W[(size_t)(kb + swk) * 256 + nb + swc + 4 * i];
        }
        __syncthreads();  // previous iteration's LDS reads done before overwrite
        #pragma unroll
        for (int i = 0; i < 4; ++i) {
            Xs[sxh + 4*i + 0][sxm] = xv[i].x;
            Xs[sxh + 4*i + 1][sxm] = xv[i].y;
            Xs[sxh + 4*i + 2][sxm] = xv[i].z;
            Xs[sxh + 4*i + 3][sxm] = xv[i].w;
            *(float4*)&Ws[swk][swc + 4*i] = wv[i];
        }
        __syncthreads();
        #pragma unroll 8
        for (int kk = 0; kk < 32; ++kk) {
            float4 a0 = *(const float4*)&Xs[kk][tm*8];
            float4 a1 = *(const float4*)&Xs[kk][tm*8 + 4];
            float4 b0 = *(const float4*)&Ws[kk][tn*8];
            float4 b1 = *(const float4*)&Ws[kk][tn*8 + 4];
            float av[8] = {a0.x,a0.y,a0.z,a0.w,a1.x,a1.y,a1.z,a1.w};
            float bw[8] = {b0.x,b0.y,b0.z,b0.w,b1.x,b1.y,b1.z,b1.w};
            #pragma unroll
            for (int i = 0; i < 8; ++i)
                #pragma unroll
                for (int j = 0; j < 8; ++j)
                    acc[i][j] = fmaf(av[i], bw[j], acc[i][j]);
        }
    }

    float4 bb0 = *(const float4*)&bias[nb + tn*8];
    float4 bb1 = *(const float4*)&bias[nb + tn*8 + 4];
    float bb[8] = {bb0.x,bb0.y,bb0.z,bb0.w,bb1.x,bb1.y,bb1.z,bb1.w};
    #pragma unroll
    for (int i = 0; i < 8; ++i) {
        const size_t row = (size_t)(mb + tm*8 + i);
        float4 o0 = {acc[i][0]+bb[0], acc[i][1]+bb[1], acc[i][2]+bb[2], acc[i][3]+bb[3]};
        float4 o1 = {acc[i][4]+bb[4], acc[i][5]+bb[5], acc[i][6]+bb[6], acc[i][7]+bb[7]};
        *(float4*)&Y[row*256 + nb + tn*8]     = o0;
        *(float4*)&Y[row*256 + nb + tn*8 + 4] = o1;
    }
}

// ---------------- RMSNorm rows in place (fp32) + bf16 copy (MFMA input) ----------------
__global__ __launch_bounds__(256)
void rmsnorm_rows(float* __restrict__ X, const float* __restrict__ g,
                  __hip_bfloat16* __restrict__ Xb)
{
    const int lane = threadIdx.x & 63;
    const size_t row = (size_t)blockIdx.x * 4 + (threadIdx.x >> 6);
    float4 x = *(const float4*)&X[row*256 + lane*4];
    float ssq = fmaf(x.x, x.x, fmaf(x.y, x.y, fmaf(x.z, x.z, x.w * x.w)));
    #pragma unroll
    for (int o = 1; o < 64; o <<= 1) ssq += __shfl_xor(ssq, o, 64);
    const float r = 1.0f / sqrtf(ssq * (1.0f/256.0f) + 1e-5f);
    float4 gg = *(const float4*)&g[lane*4];
    float y0 = (x.x*r)*gg.x, y1 = (x.y*r)*gg.y, y2 = (x.z*r)*gg.z, y3 = (x.w*r)*gg.w;
    float4 y = {y0, y1, y2, y3};
    *(float4*)&X[row*256 + lane*4] = y;
    __hip_bfloat16 h0 = __float2bfloat16(y0), h1 = __float2bfloat16(y1);
    __hip_bfloat16 h2 = __float2bfloat16(y2), h3 = __float2bfloat16(y3);
    ushort4 p;
    p.x = *(unsigned short*)&h0; p.y = *(unsigned short*)&h1;
    p.z = *(unsigned short*)&h2; p.w = *(unsigned short*)&h3;
    ((ushort4*)Xb)[row*64 + lane] = p;
}

// ---------------- bf16 MFMA logits: Out[32768][4096] = fp32(clamp(Q @ K^T * 1/16)) ----
// m97 structure: 128x128 tile, BK=64, global_load_lds(16B) staging, 2 barriers/K-step.
// Swizzle (rule #21, both-sides): LDS dest linear; global SOURCE slot pre-permuted by
// the involution slot^=row&7; ds_read applies the same XOR -> conflict-free b128 reads.
// Epilogue: LDS-bounce (reuses staging LDS) -> full-row dwordx4 coalesced stores.
__device__ __forceinline__ void load_lds16(const void* g, void* l) {
    __builtin_amdgcn_global_load_lds((const __attribute__((address_space(1))) unsigned int*)g,
                                     (__attribute__((address_space(3))) unsigned int*)l, 16, 0, 0);
}

__global__ __launch_bounds__(256, 2)
void mfma_logits(const __hip_bfloat16* __restrict__ Qb, const __hip_bfloat16* __restrict__ Kb,
                 float* __restrict__ Out)
{
    // 32 KB shared: staging A/B tiles during K-loop, then fp32 bounce tile in epilogue.
    __shared__ __align__(16) char smem[32768];
    __hip_bfloat16* Asm = (__hip_bfloat16*)smem;            // [128 rows][64 k] bf16, 16KB
    __hip_bfloat16* Bsm = (__hip_bfloat16*)(smem + 16384);  // [128 rows][64 k] bf16, 16KB
    float*          Eps = (float*)smem;                     // [64 rows][128 cols] fp32, 32KB

    const int t    = threadIdx.x;
    const int lane = t & 63;
    const int w    = t >> 6;
    const int wm = w >> 1, wn = w & 1;      // 2x2 wave grid of 64x64 quadrants
    const int mb = blockIdx.x * 128;
    const int nb = blockIdx.y * 128;

    // --- staging geometry: row = i*32 + (t>>3); within-row slot written at (t&7)
    // holds global slot (t&7)^((t>>3)&7)  [involution, row-local] ---
    const int grow   = t >> 3;                       // + i*32 per issue
    const int gslot  = (t & 7) ^ ((t >> 3) & 7);
    const __hip_bfloat16* gA = Qb + (size_t)(mb + grow) * 256 + gslot * 8;
    const __hip_bfloat16* gB = Kb + (size_t)(nb + grow) * 256 + gslot * 8;
    __hip_bfloat16* lA = &Asm[w * 512];              // + i*2048 per issue (bf16 elems)
    __hip_bfloat16* lB = &Bsm[w * 512];

    // --- fragment geometry (guide §3): fr = lane&15 row-in-16, kq = lane>>4 ---
    const int fr = lane & 15;
    const int kq = lane >> 4;
    const int rswz = lane & 7;                       // row&7 for all our fragment rows
    const int ra0 = (wm * 64 + fr) * 64;             // A base elem offset (row*64)
    const int rb0 = (wn * 64 + fr) * 64;

    f32x4 acc[4][4];
    #pragma unroll
    for (int mi = 0; mi < 4; ++mi)
        #pragma unroll
        for (int ni = 0; ni < 4; ++ni) {
            acc[mi][ni][0] = 0.f; acc[mi][ni][1] = 0.f;
            acc[mi][ni][2] = 0.f; acc[mi][ni][3] = 0.f;
        }

    for (int ks = 0; ks < 4; ++ks) {
        const int k0 = ks * 64;
        #pragma unroll
        for (int i = 0; i < 4; ++i) {
            load_lds16(gA + (size_t)i * 32 * 256 + k0, lA + i * 2048);
            load_lds16(gB + (size_t)i * 32 * 256 + k0, lB + i * 2048);
        }
        __syncthreads();   // compiler drains vmcnt(0) before s_barrier [m97 evidence]

        #pragma unroll
        for (int kh = 0; kh < 2; ++kh) {            // k = ks*64 + kh*32 (ascending ==
            bf16x8 af[4], bg[4];                    //  R4/R5 order -> bit-identical acc)
            #pragma unroll
            for (int mi = 0; mi < 4; ++mi)
                af[mi] = *(const bf16x8*)&Asm[ra0 + mi*16*64 + (((kh<<2) + kq) ^ rswz) * 8];
            #pragma unroll
            for (int ni = 0; ni < 4; ++ni)
                bg[ni] = *(const bf16x8*)&Bsm[rb0 + ni*16*64 + (((kh<<2) + kq) ^ rswz) * 8];
            #pragma unroll
            for (int mi = 0; mi < 4; ++mi)
                #pragma unroll
                for (int ni = 0; ni < 4; ++ni)
                    acc[mi][ni] = __builtin_amdgcn_mfma_f32_16x16x32_bf16(
                        af[mi], bg[ni], acc[mi][ni], 0, 0, 0);
        }
        __syncthreads();   // LDS reads done before next K-step overwrites / epilogue
    }

    // ---- epilogue: LDS bounce -> coalesced full-row dwordx4 stores ----
    // C/D layout: col = lane&15, row = (lane>>4)*4 + j  [guide §3, m89-verified]
    // Scale+clamp applied BEFORE the bounce, same ops/order as R5 -> bit-identical.
    const int cr = (lane >> 4) * 4;
    const int cc = lane & 15;
    #pragma unroll
    for (int c = 0; c < 2; ++c) {                    // chunk: rows [c*64, c*64+64)
        if (wm == c) {
            #pragma unroll
            for (int mi = 0; mi < 4; ++mi)
                #pragma unroll
                for (int ni = 0; ni < 4; ++ni) {
                    const int lrow = mi*16 + cr;                  // 0..63 within chunk
                    const int lcol = wn*64 + ni*16 + cc;          // 0..127
                    #pragma unroll
                    for (int j = 0; j < 4; ++j) {
                        float v = acc[mi][ni][j] * 0.0625f;
                        v = fminf(fmaxf(v, -16.0f), 16.0f);
                        Eps[(lrow + j) * 128 + lcol] = v;
                    }
                }
        }
        __syncthreads();   // bounce tile complete (all threads reach)
        #pragma unroll
        for (int it = 0; it < 8; ++it) {
            const int p   = it * 1024 + t * 4;       // linear word index in [64][128]
            const int row = p >> 7;
            const int col = p & 127;
            float4 v = *(const float4*)&Eps[p];
            *(float4*)&Out[(size_t)(mb + c*64 + row) * 4096 + nb + col] = v;
        }
        __syncthreads();   // chunk read done before next chunk overwrites
    }
}

// ---------------- FROZEN canonical fp32 dot (argmax determinism anchor) ----------------
// DO NOT change the summation structure in future rounds. R3/R4/R5 PASSED with this
// exact sequence (0 argmax flips vs numpy on the fixed dataset) — keep bit-identical.
__device__ __forceinline__ float dot256_f32(const float* __restrict__ a, const float* __restrict__ b)
{
    float s0 = 0.f, s1 = 0.f, s2 = 0.f, s3 = 0.f;
    #pragma unroll 8
    for (int j = 0; j < 64; ++j) {
        float4 x = ((const float4*)a)[j];
        float4 y = ((const float4*)b)[j];
        s0 = fmaf(x.x, y.x, s0);
        s1 = fmaf(x.y, y.y, s1);
        s2 = fmaf(x.z, y.z, s2);
        s3 = fmaf(x.w, y.w, s3);
    }
    return (s0 + s1) + (s2 + s3);
}

// ---------------- refinement: compact candidates, then wave-parallel frozen dots ------
// One wave per token row. Candidates (logit >= rowmax - 0.5; margin >> bf16-MFMA error
// ~0.1 so the true fp32 argmax is provably included) are compacted into an LDS list,
// then dispatched ONE PER LANE in a single exec pass — same dot256_f32 per candidate,
// bit-identical values; max-with-min-idx-tiebreak reduce is order-independent.
__global__ __launch_bounds__(256)
void refine_argmax(const float* __restrict__ L, const float* __restrict__ Qf,
                   const float* __restrict__ Kf, const float* __restrict__ Vf,
                   float* __restrict__ OutIdx, float* __restrict__ Zq,
                   float* __restrict__ Zq2)
{
    __shared__ int cnt[4];
    __shared__ int list[4][256];
    const int lane = threadIdx.x & 63;
    const int w    = threadIdx.x >> 6;
    const size_t row = (size_t)blockIdx.x * 4 + w;
    const float4* lrow = (const float4*)(L + row * 4096);

    // phase 1: coalesced row read + row max
    float4 u[16];
    float vmax = -INFINITY;
    #pragma unroll
    for (int i = 0; i < 16; ++i) {
        u[i] = lrow[i*64 + lane];
        vmax = fmaxf(vmax, fmaxf(fmaxf(u[i].x, u[i].y), fmaxf(u[i].z, u[i].w)));
    }
    #pragma unroll
    for (int o = 1; o < 64; o <<= 1) vmax = fmaxf(vmax, __shfl_xor(vmax, o, 64));

    if (lane == 0) cnt[w] = 0;
    __syncthreads();   // unconditional: every thread reaches this

    // phase 2: candidate compaction (no dots here — cheap VALU + rare LDS atomics)
    const float thr = vmax - 0.5f;
    #pragma unroll
    for (int i = 0; i < 16; ++i) {
        const float* pe = (const float*)&u[i];
        #pragma unroll
        for (int e = 0; e < 4; ++e) {
            if (pe[e] >= thr) {
                int slot = atomicAdd(&cnt[w], 1);
                if (slot < 256) list[w][slot] = (i*64 + lane)*4 + e;
            }
        }
    }
    __syncthreads();   // unconditional

    // phase 3: one candidate per lane, all dots in ONE exec pass
    int m = cnt[w]; if (m > 256) m = 256;   // P(overflow) ~ 0 for this fixed dataset
    float bv = -INFINITY;
    int   bi = 0x7fffffff;
    const float* qrow = Qf + row * 256;
    for (int base = 0; base < m; base += 64) {
        const int ci = base + lane;
        if (ci < m) {
            const int c = list[w][ci];
            float rv = dot256_f32(qrow, Kf + (size_t)c * 256) * 0.0625f;
            if (rv > bv || (rv == bv && c < bi)) { bv = rv; bi = c; }
        }
    }
    #pragma unroll
    for (int o = 1; o < 64; o <<= 1) {
        float ov = __shfl_xor(bv, o, 64);
        int   oi = __shfl_xor(bi, o, 64);
        if (ov > bv || (ov == bv && oi < bi)) { bv = ov; bi = oi; }
    }

    // safety clamp: never read OOB even on broken logits
    if (bi < 0) bi = 0;
    if (bi > 4095) bi = 4095;

    if (lane == 0) OutIdx[row] = (float)bi;   // idx as fp32 value in the fp32 out buffer

    // z_q = z_q_2 = v[idx]   (STE term cancels exactly in fp32: (0-s)+s == 0)
    float4 vv = ((const float4*)(Vf + (size_t)bi * 256))[lane];
    ((float4*)Zq)[row*64 + lane]  = vv;
    ((float4*)Zq2)[row*64 + lane] = vv;
}

extern "C" void kernel_launch(void* const* d_in, const int* in_sizes, int n_in,
                              void* d_out, int out_size, void* d_ws, size_t ws_size,
                              hipStream_t stream)
{
    (void)in_sizes; (void)n_in; (void)out_size;
    const float* hs = (const float*)d_in[0];
    const float* cb = (const float*)d_in[1];
    const float* wq = (const float*)d_in[2];
    const float* bq = (const float*)d_in[3];
    const float* wk = (const float*)d_in[4];
    const float* bk = (const float*)d_in[5];
    const float* wv = (const float*)d_in[6];
    const float* bv = (const float*)d_in[7];
    const float* gq = (const float*)d_in[8];
    const float* gk = (const float*)d_in[9];
    float* out = (float*)d_out;   // fp32: reference outputs are fp32/int32

    if (ws_size < 60817408u) return;  // need ~58 MB scratch; fail loudly if absent

    char* ws = (char*)d_ws;
    float* qf = (float*)ws;                                   // 32 MB: q raw -> q_norm (in place)
    float* kf = (float*)(ws + 33554432);                      //  4 MB: k raw -> k_norm (in place)
    float* vf = (float*)(ws + 37748736);                      //  4 MB: v
    __hip_bfloat16* qb = (__hip_bfloat16*)(ws + 41943040);    // 16 MB: q_norm bf16
    __hip_bfloat16* kb = (__hip_bfloat16*)(ws + 58720256);    //  2 MB: k_norm bf16

    gemm_xw256<<<dim3(32, 2),  256, 0, stream>>>(cb, wk, bk, kf);
    gemm_xw256<<<dim3(32, 2),  256, 0, stream>>>(cb, wv, bv, vf);
    gemm_xw256<<<dim3(256, 2), 256, 0, stream>>>(hs, wq, bq, qf);
    rmsnorm_rows<<<1024, 256, 0, stream>>>(kf, gk, kb);
    rmsnorm_rows<<<8192, 256, 0, stream>>>(qf, gq, qb);
    mfma_logits<<<dim3(256, 32), 256, 0, stream>>>(qb, kb, out);
    refine_argmax<<<8192, 256, 0, stream>>>(out, qf, kf, vf,
        out + 134217728ull,   // idx   [32768]
        out + 134250496ull,   // z_q   [32768*256]
        out + 142639104ull);  // z_q_2 [32768*256]
}